// Round 1
// baseline (201.738 us; speedup 1.0000x reference)
//
#include <hip/hip_runtime.h>
#include <hip/hip_bf16.h>

// Problem sizes (fixed by the reference)
#define LROWS 8192
#define BROWS 4096
#define DDIM  1024

typedef __bf16 bf16;
typedef __attribute__((ext_vector_type(8))) __bf16 bf16x8;
typedef __attribute__((ext_vector_type(4))) float f32x4;

// address-space-qualified pointer typedefs for global_load_lds
typedef const unsigned int __attribute__((address_space(1))) gu32;
typedef unsigned int       __attribute__((address_space(3))) su32;

__device__ inline unsigned short f2bf_bits(float f) {
    bf16 h = (bf16)f;   // RNE fptrunc
    return __builtin_bit_cast(unsigned short, h);
}

// ---------------- init: zero the scalar output ----------------
__global__ void init_kernel(float* out) {
    if (threadIdx.x == 0) out[0] = 0.0f;
}

// ---------------- fp32 -> bf16 cast of pred and gt ----------------
// one thread = one float4 -> ushort4 (4 elems). First half pred, second half gt.
__global__ void cast_kernel(const float4* __restrict__ pred,
                            const float4* __restrict__ gt,
                            ushort4* __restrict__ opred,
                            ushort4* __restrict__ ogt) {
    const int nq = BROWS * DDIM / 4;  // 1048576 float4 per matrix
    int t = blockIdx.x * blockDim.x + threadIdx.x;
    const float4* src;
    ushort4* dst;
    int i;
    if (t < nq) { src = pred; dst = opred; i = t; }
    else        { src = gt;   dst = ogt;   i = t - nq; }
    float4 v = src[i];
    ushort4 r;
    r.x = f2bf_bits(v.x);
    r.y = f2bf_bits(v.y);
    r.z = f2bf_bits(v.z);
    r.w = f2bf_bits(v.w);
    dst[i] = r;
}

// ---------------- pos[i] = dot(pred[i], gt[i]) in fp32 ----------------
// one block (256 threads) per row; thread t takes float4 #t of the row (D=1024 -> 256 float4)
__global__ void pos_kernel(const float4* __restrict__ pred,
                           const float4* __restrict__ gt,
                           float* __restrict__ pos) {
    __shared__ float sred[4];
    int row = blockIdx.x;
    int t = threadIdx.x;
    float4 a = pred[row * 256 + t];
    float4 b = gt[row * 256 + t];
    float s = a.x * b.x + a.y * b.y + a.z * b.z + a.w * b.w;
    #pragma unroll
    for (int o = 32; o > 0; o >>= 1) s += __shfl_down(s, o, 64);
    if ((t & 63) == 0) sred[t >> 6] = s;
    __syncthreads();
    if (t == 0) pos[row] = sred[0] + sred[1] + sred[2] + sred[3];
}

// ---------------- local loss: -(1/L) * sum(q_hat * q_real) ----------------
__global__ void local_kernel(const float4* __restrict__ qh,
                             const float4* __restrict__ qr,
                             float* __restrict__ out) {
    __shared__ float sred[4];
    const int total = LROWS * DDIM / 4;  // 2097152
    int t = blockIdx.x * blockDim.x + threadIdx.x;
    int stride = gridDim.x * blockDim.x;
    float s = 0.0f;
    for (int i = t; i < total; i += stride) {
        float4 a = qh[i];
        float4 b = qr[i];
        s += a.x * b.x + a.y * b.y + a.z * b.z + a.w * b.w;
    }
    #pragma unroll
    for (int o = 32; o > 0; o >>= 1) s += __shfl_down(s, o, 64);
    int lane = threadIdx.x & 63, w = threadIdx.x >> 6;
    if (lane == 0) sred[w] = s;
    __syncthreads();
    if (threadIdx.x == 0) {
        float bs = sred[0] + sred[1] + sred[2] + sred[3];
        atomicAdd(out, -bs * (1.0f / (float)LROWS));
    }
}

// ---------------- hinge GEMM: sum_ij max(0, <pred_i,gt_j> - pos_i + 1) ----------------
// m97 structure: 128x128 block tile, BK=32, 4 waves, each wave 64x64 (4x4 of 16x16x32 MFMA),
// global_load_lds width=16 staging, 2 barriers per K-step.
__global__ __launch_bounds__(256) void hinge_gemm(
    const bf16* __restrict__ A,    // pred_bf16 [BROWS][DDIM] row-major
    const bf16* __restrict__ Bm,   // gt_bf16   [BROWS][DDIM] row-major
    const float* __restrict__ pos, // [BROWS]
    float* __restrict__ out) {
    __shared__ bf16 As[128 * 32];  // 8 KB
    __shared__ bf16 Bs[128 * 32];  // 8 KB
    __shared__ float pos_s[128];
    __shared__ float sred[4];

    const int bm = blockIdx.y;  // row block (pred rows)
    const int bn = blockIdx.x;  // col block (gt rows)
    const int tid = threadIdx.x;
    const int lane = tid & 63;
    const int wave = tid >> 6;
    const int wm = wave >> 1;   // 0..1  wave row within block tile
    const int wn = wave & 1;    // 0..1  wave col

    if (tid < 128) pos_s[tid] = pos[bm * 128 + tid];

    // staging lane mapping: lane i -> LDS byte chunkbase + 16*i
    // row within chunk = lane/4, 16B piece within 64B row = lane%4
    const int lrow = lane >> 2;        // 0..15
    const int lcol = (lane & 3) * 8;   // element offset in row (8 bf16 = 16B)

    const bf16* Abase = A + (size_t)(bm * 128) * DDIM;
    const bf16* Bbase = Bm + (size_t)(bn * 128) * DDIM;

    f32x4 zero = {0.0f, 0.0f, 0.0f, 0.0f};
    f32x4 acc[4][4];
    #pragma unroll
    for (int i = 0; i < 4; i++)
        #pragma unroll
        for (int j = 0; j < 4; j++) acc[i][j] = zero;

    for (int k0 = 0; k0 < DDIM; k0 += 32) {
        // stage A and B tiles: 8 chunks of 1024B each; wave w does chunks 2w, 2w+1
        #pragma unroll
        for (int s = 0; s < 2; s++) {
            int chunk = wave * 2 + s;
            int row = chunk * 16 + lrow;
            __builtin_amdgcn_global_load_lds(
                (gu32*)(Abase + (size_t)row * DDIM + k0 + lcol),
                (su32*)(As + chunk * 512), 16, 0, 0);
            __builtin_amdgcn_global_load_lds(
                (gu32*)(Bbase + (size_t)row * DDIM + k0 + lcol),
                (su32*)(Bs + chunk * 512), 16, 0, 0);
        }
        __syncthreads();

        const int koff = (lane >> 4) * 8;  // A/B operand: k = quad*8 + j
        const int rsel = lane & 15;        // m (or n) index
        bf16x8 af[4], bg[4];
        #pragma unroll
        for (int mt = 0; mt < 4; mt++)
            af[mt] = *(const bf16x8*)&As[(wm * 64 + mt * 16 + rsel) * 32 + koff];
        #pragma unroll
        for (int nt = 0; nt < 4; nt++)
            bg[nt] = *(const bf16x8*)&Bs[(wn * 64 + nt * 16 + rsel) * 32 + koff];
        #pragma unroll
        for (int mt = 0; mt < 4; mt++)
            #pragma unroll
            for (int nt = 0; nt < 4; nt++)
                acc[mt][nt] = __builtin_amdgcn_mfma_f32_16x16x32_bf16(
                    af[mt], bg[nt], acc[mt][nt], 0, 0, 0);
        __syncthreads();
    }

    // epilogue: hinge + block reduction
    // C/D layout: col = lane&15, row = (lane>>4)*4 + reg   [verified m89/m91]
    float s = 0.0f;
    const int rowq = (lane >> 4) * 4;
    #pragma unroll
    for (int mt = 0; mt < 4; mt++) {
        #pragma unroll
        for (int nt = 0; nt < 4; nt++) {
            #pragma unroll
            for (int r = 0; r < 4; r++) {
                int lr = wm * 64 + mt * 16 + rowq + r;  // local row in [0,128)
                float v = acc[mt][nt][r] - pos_s[lr] + 1.0f;
                s += fmaxf(v, 0.0f);
            }
        }
    }
    #pragma unroll
    for (int o = 32; o > 0; o >>= 1) s += __shfl_down(s, o, 64);
    if (lane == 0) sred[wave] = s;
    __syncthreads();
    if (tid == 0) atomicAdd(out, sred[0] + sred[1] + sred[2] + sred[3]);
}

extern "C" void kernel_launch(void* const* d_in, const int* in_sizes, int n_in,
                              void* d_out, int out_size, void* d_ws, size_t ws_size,
                              hipStream_t stream) {
    const float* q_hat  = (const float*)d_in[0];
    const float* q_real = (const float*)d_in[1];
    const float* gt     = (const float*)d_in[2];  // encoded_gt
    const float* pred   = (const float*)d_in[3];  // encoded_pred
    float* out = (float*)d_out;

    // workspace layout: pred_bf16 (8MB) | gt_bf16 (8MB) | pos (16KB)
    char* ws = (char*)d_ws;
    bf16* pred_b = (bf16*)ws;
    bf16* gt_b   = (bf16*)(ws + (size_t)BROWS * DDIM * 2);
    float* pos   = (float*)(ws + (size_t)BROWS * DDIM * 4);

    hipLaunchKernelGGL(init_kernel, dim3(1), dim3(64), 0, stream, out);

    const int cast_threads = 2 * BROWS * DDIM / 4;  // 2M
    hipLaunchKernelGGL(cast_kernel, dim3(cast_threads / 256), dim3(256), 0, stream,
                       (const float4*)pred, (const float4*)gt,
                       (ushort4*)pred_b, (ushort4*)gt_b);

    hipLaunchKernelGGL(pos_kernel, dim3(BROWS), dim3(256), 0, stream,
                       (const float4*)pred, (const float4*)gt, pos);

    hipLaunchKernelGGL(local_kernel, dim3(2048), dim3(256), 0, stream,
                       (const float4*)q_hat, (const float4*)q_real, out);

    hipLaunchKernelGGL(hinge_gemm, dim3(32, 32), dim3(256), 0, stream,
                       pred_b, gt_b, pos, out);
}

// Round 2
// 168.240 us; speedup vs baseline: 1.1991x; 1.1991x over previous
//
#include <hip/hip_runtime.h>
#include <hip/hip_bf16.h>

// Problem sizes (fixed by the reference)
#define LROWS 8192
#define BROWS 4096
#define DDIM  1024

typedef __bf16 bf16;
typedef __attribute__((ext_vector_type(8))) __bf16 bf16x8;
typedef __attribute__((ext_vector_type(4))) float f32x4;

// address-space-qualified pointer typedefs for global_load_lds
typedef const unsigned int __attribute__((address_space(1))) gu32;
typedef unsigned int       __attribute__((address_space(3))) su32;

__device__ inline unsigned short f2bf_bits(float f) {
    bf16 h = (bf16)f;   // RNE fptrunc
    return __builtin_bit_cast(unsigned short, h);
}

// ---------------- prep: fp32->bf16 cast of pred/gt + pos[i]=dot(pred_i,gt_i) ----------------
// one block (256 threads) per row; thread t handles float4 #t of the row (D=1024 -> 256 float4)
__global__ __launch_bounds__(256) void prep_kernel(
    const float4* __restrict__ pred,
    const float4* __restrict__ gt,
    ushort4* __restrict__ opred,
    ushort4* __restrict__ ogt,
    float* __restrict__ pos) {
    __shared__ float sred[4];
    const int row = blockIdx.x;
    const int t = threadIdx.x;
    const int idx = row * 256 + t;
    float4 p = pred[idx];
    float4 g = gt[idx];
    // cast both to bf16
    ushort4 pb, gb;
    pb.x = f2bf_bits(p.x); pb.y = f2bf_bits(p.y); pb.z = f2bf_bits(p.z); pb.w = f2bf_bits(p.w);
    gb.x = f2bf_bits(g.x); gb.y = f2bf_bits(g.y); gb.z = f2bf_bits(g.z); gb.w = f2bf_bits(g.w);
    opred[idx] = pb;
    ogt[idx] = gb;
    // fp32 diagonal dot
    float s = p.x * g.x + p.y * g.y + p.z * g.z + p.w * g.w;
    #pragma unroll
    for (int o = 32; o > 0; o >>= 1) s += __shfl_down(s, o, 64);
    if ((t & 63) == 0) sred[t >> 6] = s;
    __syncthreads();
    if (t == 0) pos[row] = sred[0] + sred[1] + sred[2] + sred[3];
}

// ---------------- hinge GEMM + fused local loss ----------------
// sum_ij max(0, <pred_i,gt_j> - pos_i + 1)  - (1/L) sum(q_hat*q_real)
// m97 structure: 128x128 block tile, BK=32, 4 waves, each wave 64x64 (4x4 of 16x16x32 MFMA),
// global_load_lds width=16 staging, XOR-swizzled LDS chunks to kill bank conflicts.
// Each block additionally streams its 1/1024 slice of q_hat*q_real (pure HBM work that
// overlaps the compute-bound GEMM).
__global__ __launch_bounds__(256) void hinge_gemm(
    const bf16* __restrict__ A,    // pred_bf16 [BROWS][DDIM] row-major
    const bf16* __restrict__ Bm,   // gt_bf16   [BROWS][DDIM] row-major
    const float* __restrict__ pos, // [BROWS]
    const float4* __restrict__ qh, // q_hat  as float4, 2097152 total
    const float4* __restrict__ qr, // q_real
    float* __restrict__ out) {
    __shared__ bf16 As[128 * 32];  // 8 KB (swizzled)
    __shared__ bf16 Bs[128 * 32];  // 8 KB (swizzled)
    __shared__ float pos_s[128];
    __shared__ float sred[4];

    const int bm = blockIdx.y;  // row block (pred rows)
    const int bn = blockIdx.x;  // col block (gt rows)
    const int tid = threadIdx.x;
    const int lane = tid & 63;
    const int wave = tid >> 6;
    const int wm = wave >> 1;   // 0..1  wave row within block tile
    const int wn = wave & 1;    // 0..1  wave col

    if (tid < 128) pos_s[tid] = pos[bm * 128 + tid];

    // ---- fused local loss: this block's slice of q_hat . q_real ----
    // 2048 float4 per block (8 iters x 256 threads)
    const int bid = bm * 32 + bn;
    const int qbase = bid * 2048;
    float ls = 0.0f;
    #pragma unroll
    for (int it = 0; it < 8; it++) {
        int i = qbase + it * 256 + tid;
        float4 a = qh[i];
        float4 b = qr[i];
        ls += a.x * b.x + a.y * b.y + a.z * b.z + a.w * b.w;
    }

    // staging lane mapping (swizzled): lane -> LDS chunkbase + 16*lane (fixed by HW);
    // lane fetches the global 16B piece that belongs at its swizzled slot:
    //   row-within-1KB-chunk = lane>>2, phys 16B piece p = lane&3,
    //   logical piece = p ^ ((row>>1)&3)
    const int lrow = lane >> 2;                                   // 0..15
    const int lcol = (((lane & 3) ^ ((lane >> 3) & 3)) * 8);      // element offset (8 bf16 = 16B)

    const bf16* Abase = A + (size_t)(bm * 128) * DDIM;
    const bf16* Bbase = Bm + (size_t)(bn * 128) * DDIM;

    f32x4 zero = {0.0f, 0.0f, 0.0f, 0.0f};
    f32x4 acc[4][4];
    #pragma unroll
    for (int i = 0; i < 4; i++)
        #pragma unroll
        for (int j = 0; j < 4; j++) acc[i][j] = zero;

    for (int k0 = 0; k0 < DDIM; k0 += 32) {
        // stage A and B tiles: 8 chunks of 1024B each; wave w does chunks 2w, 2w+1
        #pragma unroll
        for (int s = 0; s < 2; s++) {
            int chunk = wave * 2 + s;
            int row = chunk * 16 + lrow;
            __builtin_amdgcn_global_load_lds(
                (gu32*)(Abase + (size_t)row * DDIM + k0 + lcol),
                (su32*)(As + chunk * 512), 16, 0, 0);
            __builtin_amdgcn_global_load_lds(
                (gu32*)(Bbase + (size_t)row * DDIM + k0 + lcol),
                (su32*)(Bs + chunk * 512), 16, 0, 0);
        }
        __syncthreads();

        // MFMA fragment reads with swizzle: logical chunk q = lane>>4,
        // phys chunk = q ^ ((rsel>>1)&3)
        const int q = lane >> 4;
        const int rsel = lane & 15;
        const int koff = (q ^ ((rsel >> 1) & 3)) * 8;
        bf16x8 af[4], bg[4];
        #pragma unroll
        for (int mt = 0; mt < 4; mt++)
            af[mt] = *(const bf16x8*)&As[(wm * 64 + mt * 16 + rsel) * 32 + koff];
        #pragma unroll
        for (int nt = 0; nt < 4; nt++)
            bg[nt] = *(const bf16x8*)&Bs[(wn * 64 + nt * 16 + rsel) * 32 + koff];
        #pragma unroll
        for (int mt = 0; mt < 4; mt++)
            #pragma unroll
            for (int nt = 0; nt < 4; nt++)
                acc[mt][nt] = __builtin_amdgcn_mfma_f32_16x16x32_bf16(
                    af[mt], bg[nt], acc[mt][nt], 0, 0, 0);
        __syncthreads();
    }

    // epilogue: hinge + local partial + block reduction
    // C/D layout: col = lane&15, row = (lane>>4)*4 + reg   [verified m89/m91]
    float s = 0.0f;
    const int rowq = (lane >> 4) * 4;
    #pragma unroll
    for (int mt = 0; mt < 4; mt++) {
        #pragma unroll
        for (int nt = 0; nt < 4; nt++) {
            #pragma unroll
            for (int r = 0; r < 4; r++) {
                int lr = wm * 64 + mt * 16 + rowq + r;  // local row in [0,128)
                float v = acc[mt][nt][r] - pos_s[lr] + 1.0f;
                s += fmaxf(v, 0.0f);
            }
        }
    }
    s -= ls * (1.0f / (float)LROWS);   // fold local-loss partial into same reduction
    #pragma unroll
    for (int o = 32; o > 0; o >>= 1) s += __shfl_down(s, o, 64);
    if (lane == 0) sred[wave] = s;
    __syncthreads();
    if (tid == 0) atomicAdd(out, sred[0] + sred[1] + sred[2] + sred[3]);
}

extern "C" void kernel_launch(void* const* d_in, const int* in_sizes, int n_in,
                              void* d_out, int out_size, void* d_ws, size_t ws_size,
                              hipStream_t stream) {
    const float* q_hat  = (const float*)d_in[0];
    const float* q_real = (const float*)d_in[1];
    const float* gt     = (const float*)d_in[2];  // encoded_gt
    const float* pred   = (const float*)d_in[3];  // encoded_pred
    float* out = (float*)d_out;

    // workspace layout: pred_bf16 (8MB) | gt_bf16 (8MB) | pos (16KB)
    char* ws = (char*)d_ws;
    bf16* pred_b = (bf16*)ws;
    bf16* gt_b   = (bf16*)(ws + (size_t)BROWS * DDIM * 2);
    float* pos   = (float*)(ws + (size_t)BROWS * DDIM * 4);

    hipMemsetAsync(out, 0, sizeof(float), stream);

    hipLaunchKernelGGL(prep_kernel, dim3(BROWS), dim3(256), 0, stream,
                       (const float4*)pred, (const float4*)gt,
                       (ushort4*)pred_b, (ushort4*)gt_b, pos);

    hipLaunchKernelGGL(hinge_gemm, dim3(32, 32), dim3(256), 0, stream,
                       pred_b, gt_b, pos,
                       (const float4*)q_hat, (const float4*)q_real, out);
}

// Round 3
// 165.444 us; speedup vs baseline: 1.2194x; 1.0169x over previous
//
#include <hip/hip_runtime.h>
#include <hip/hip_bf16.h>

// Problem sizes (fixed by the reference)
#define LROWS 8192
#define BROWS 4096
#define DDIM  1024

typedef __bf16 bf16;
typedef __attribute__((ext_vector_type(8))) __bf16 bf16x8;
typedef __attribute__((ext_vector_type(4))) float f32x4;

// address-space-qualified pointer typedefs for global_load_lds
typedef const unsigned int __attribute__((address_space(1))) gu32;
typedef unsigned int       __attribute__((address_space(3))) su32;

__device__ inline unsigned short f2bf_bits(float f) {
    bf16 h = (bf16)f;   // RNE fptrunc
    return __builtin_bit_cast(unsigned short, h);
}

// ---------------- prep: fp32->bf16 cast of pred/gt + pos[i]=dot(pred_i,gt_i) ----------------
// one block (256 threads) per row; thread t handles float4 #t of the row (D=1024 -> 256 float4)
// block 0 also zero-initializes the output scalar (hinge_gemm runs after us in stream order).
__global__ __launch_bounds__(256) void prep_kernel(
    const float4* __restrict__ pred,
    const float4* __restrict__ gt,
    ushort4* __restrict__ opred,
    ushort4* __restrict__ ogt,
    float* __restrict__ pos,
    float* __restrict__ out) {
    __shared__ float sred[4];
    const int row = blockIdx.x;
    const int t = threadIdx.x;
    if (row == 0 && t == 0) out[0] = 0.0f;
    const int idx = row * 256 + t;
    float4 p = pred[idx];
    float4 g = gt[idx];
    // cast both to bf16
    ushort4 pb, gb;
    pb.x = f2bf_bits(p.x); pb.y = f2bf_bits(p.y); pb.z = f2bf_bits(p.z); pb.w = f2bf_bits(p.w);
    gb.x = f2bf_bits(g.x); gb.y = f2bf_bits(g.y); gb.z = f2bf_bits(g.z); gb.w = f2bf_bits(g.w);
    opred[idx] = pb;
    ogt[idx] = gb;
    // fp32 diagonal dot
    float s = p.x * g.x + p.y * g.y + p.z * g.z + p.w * g.w;
    #pragma unroll
    for (int o = 32; o > 0; o >>= 1) s += __shfl_down(s, o, 64);
    if ((t & 63) == 0) sred[t >> 6] = s;
    __syncthreads();
    if (t == 0) pos[row] = sred[0] + sred[1] + sred[2] + sred[3];
}

// ---------------- hinge GEMM + fused local loss ----------------
// sum_ij max(0, <pred_i,gt_j> - pos_i + 1)  - (1/L) sum(q_hat*q_real)
// m97 structure: 128x128 block tile, BK=32, 4 waves, each wave 64x64 (4x4 of 16x16x32 MFMA),
// global_load_lds width=16 staging, XOR-swizzled LDS chunks (0 bank conflicts, verified R2).
// The local-loss q streams are interleaved one float4-pair per 128-k group so they ride
// in flight WITH that group's staging loads (drained by the same barrier vmcnt(0)).
__global__ __launch_bounds__(256) void hinge_gemm(
    const bf16* __restrict__ A,    // pred_bf16 [BROWS][DDIM] row-major
    const bf16* __restrict__ Bm,   // gt_bf16   [BROWS][DDIM] row-major
    const float* __restrict__ pos, // [BROWS]
    const float4* __restrict__ qh, // q_hat  as float4, 2097152 total
    const float4* __restrict__ qr, // q_real
    float* __restrict__ out) {
    __shared__ bf16 As[128 * 32];  // 8 KB (swizzled)
    __shared__ bf16 Bs[128 * 32];  // 8 KB (swizzled)
    __shared__ float pos_s[128];
    __shared__ float sred[4];

    const int bm = blockIdx.y;  // row block (pred rows)
    const int bn = blockIdx.x;  // col block (gt rows)
    const int tid = threadIdx.x;
    const int lane = tid & 63;
    const int wave = tid >> 6;
    const int wm = wave >> 1;   // 0..1  wave row within block tile
    const int wn = wave & 1;    // 0..1  wave col

    if (tid < 128) pos_s[tid] = pos[bm * 128 + tid];

    // fused local loss: this block's 2048-float4 slice of q_hat . q_real
    const int bid = bm * 32 + bn;
    const int qbase = bid * 2048 + tid;
    float ls = 0.0f;

    // staging lane mapping (swizzled): lane -> LDS chunkbase + 16*lane (fixed by HW);
    // lane fetches the global 16B piece that belongs at its swizzled slot:
    //   row-within-1KB-chunk = lane>>2, phys 16B piece p = lane&3,
    //   logical piece = p ^ ((row>>1)&3)
    const int lrow = lane >> 2;                                   // 0..15
    const int lcol = (((lane & 3) ^ ((lane >> 3) & 3)) * 8);      // element offset (8 bf16 = 16B)

    const bf16* Abase = A + (size_t)(bm * 128) * DDIM;
    const bf16* Bbase = Bm + (size_t)(bn * 128) * DDIM;

    f32x4 zero = {0.0f, 0.0f, 0.0f, 0.0f};
    f32x4 acc[4][4];
    #pragma unroll
    for (int i = 0; i < 4; i++)
        #pragma unroll
        for (int j = 0; j < 4; j++) acc[i][j] = zero;

    const int q = lane >> 4;
    const int rsel = lane & 15;
    const int koff = (q ^ ((rsel >> 1) & 3)) * 8;

    for (int k0 = 0; k0 < DDIM; k0 += 128) {   // 8 groups of 4 BK=32 steps
        float4 qa, qb;
        #pragma unroll
        for (int kk = 0; kk < 4; kk++) {
            const int k = k0 + kk * 32;
            // stage A and B tiles: 8 chunks of 1024B each; wave w does chunks 2w, 2w+1
            #pragma unroll
            for (int s = 0; s < 2; s++) {
                int chunk = wave * 2 + s;
                int row = chunk * 16 + lrow;
                __builtin_amdgcn_global_load_lds(
                    (gu32*)(Abase + (size_t)row * DDIM + k + lcol),
                    (su32*)(As + chunk * 512), 16, 0, 0);
                __builtin_amdgcn_global_load_lds(
                    (gu32*)(Bbase + (size_t)row * DDIM + k + lcol),
                    (su32*)(Bs + chunk * 512), 16, 0, 0);
            }
            if (kk == 0) {
                // one q-pair per group, in flight alongside this group's staging loads
                qa = qh[qbase + (k0 >> 7) * 256];
                qb = qr[qbase + (k0 >> 7) * 256];
            }
            __syncthreads();
            if (kk == 0)
                ls += qa.x * qb.x + qa.y * qb.y + qa.z * qb.z + qa.w * qb.w;

            // MFMA fragment reads with swizzle: logical chunk q = lane>>4,
            // phys chunk = q ^ ((rsel>>1)&3)
            bf16x8 af[4], bg[4];
            #pragma unroll
            for (int mt = 0; mt < 4; mt++)
                af[mt] = *(const bf16x8*)&As[(wm * 64 + mt * 16 + rsel) * 32 + koff];
            #pragma unroll
            for (int nt = 0; nt < 4; nt++)
                bg[nt] = *(const bf16x8*)&Bs[(wn * 64 + nt * 16 + rsel) * 32 + koff];
            #pragma unroll
            for (int mt = 0; mt < 4; mt++)
                #pragma unroll
                for (int nt = 0; nt < 4; nt++)
                    acc[mt][nt] = __builtin_amdgcn_mfma_f32_16x16x32_bf16(
                        af[mt], bg[nt], acc[mt][nt], 0, 0, 0);
            __syncthreads();
        }
    }

    // epilogue: hinge + local partial + block reduction
    // C/D layout: col = lane&15, row = (lane>>4)*4 + reg   [verified m89/m91]
    float s = 0.0f;
    const int rowq = (lane >> 4) * 4;
    #pragma unroll
    for (int mt = 0; mt < 4; mt++) {
        #pragma unroll
        for (int nt = 0; nt < 4; nt++) {
            #pragma unroll
            for (int r = 0; r < 4; r++) {
                int lr = wm * 64 + mt * 16 + rowq + r;  // local row in [0,128)
                float v = acc[mt][nt][r] - pos_s[lr] + 1.0f;
                s += fmaxf(v, 0.0f);
            }
        }
    }
    s -= ls * (1.0f / (float)LROWS);   // fold local-loss partial into same reduction
    #pragma unroll
    for (int o = 32; o > 0; o >>= 1) s += __shfl_down(s, o, 64);
    if (lane == 0) sred[wave] = s;
    __syncthreads();
    if (tid == 0) atomicAdd(out, sred[0] + sred[1] + sred[2] + sred[3]);
}

extern "C" void kernel_launch(void* const* d_in, const int* in_sizes, int n_in,
                              void* d_out, int out_size, void* d_ws, size_t ws_size,
                              hipStream_t stream) {
    const float* q_hat  = (const float*)d_in[0];
    const float* q_real = (const float*)d_in[1];
    const float* gt     = (const float*)d_in[2];  // encoded_gt
    const float* pred   = (const float*)d_in[3];  // encoded_pred
    float* out = (float*)d_out;

    // workspace layout: pred_bf16 (8MB) | gt_bf16 (8MB) | pos (16KB)
    char* ws = (char*)d_ws;
    bf16* pred_b = (bf16*)ws;
    bf16* gt_b   = (bf16*)(ws + (size_t)BROWS * DDIM * 2);
    float* pos   = (float*)(ws + (size_t)BROWS * DDIM * 4);

    hipLaunchKernelGGL(prep_kernel, dim3(BROWS), dim3(256), 0, stream,
                       (const float4*)pred, (const float4*)gt,
                       (ushort4*)pred_b, (ushort4*)gt_b, pos, out);

    hipLaunchKernelGGL(hinge_gemm, dim3(32, 32), dim3(256), 0, stream,
                       pred_b, gt_b, pos,
                       (const float4*)q_hat, (const float4*)q_real, out);
}

// Round 4
// 163.165 us; speedup vs baseline: 1.2364x; 1.0140x over previous
//
#include <hip/hip_runtime.h>
#include <hip/hip_bf16.h>

// Problem sizes (fixed by the reference)
#define LROWS 8192
#define BROWS 4096
#define DDIM  1024

typedef __attribute__((ext_vector_type(4))) float f32x4;

// address-space-qualified pointer typedefs for global_load_lds
typedef const unsigned int __attribute__((address_space(1))) gu32;
typedef unsigned int       __attribute__((address_space(3))) su32;

// pack 4 floats -> 4 fp8 e4m3 bytes (OCP e4m3fn on gfx950)
__device__ inline unsigned int pack_fp8x4(float4 v) {
    unsigned int w = 0;
    w = __builtin_amdgcn_cvt_pk_fp8_f32(v.x, v.y, w, false);  // bytes 0,1
    w = __builtin_amdgcn_cvt_pk_fp8_f32(v.z, v.w, w, true);   // bytes 2,3
    return w;
}

// ---------------- prep: fp32->fp8 cast + pos diag dots + local-loss partials ----------------
// one block per pred/gt row (4096 blocks). Each block ALSO streams its 1/4096 slice of
// q_hat/q_real (512 float4 each) — pure HBM streaming at full rate here, instead of
// poisoning the GEMM's barrier-drained K-loop (R2/R3 lesson). Partials go to ws (plain
// stores); hinge folds them. Block 0 zero-inits out (hinge runs after in stream order).
__global__ __launch_bounds__(256) void prep_kernel(
    const float4* __restrict__ pred,
    const float4* __restrict__ gt,
    unsigned int* __restrict__ opred,   // fp8, 256 uints per row
    unsigned int* __restrict__ ogt,
    const float4* __restrict__ qh,
    const float4* __restrict__ qr,
    float* __restrict__ pos,
    float* __restrict__ lpart,          // [4096] per-block local-loss partials
    float* __restrict__ out) {
    __shared__ float sred[4], sred2[4];
    const int row = blockIdx.x;
    const int t = threadIdx.x;
    if (row == 0 && t == 0) out[0] = 0.0f;

    const int idx = row * 256 + t;
    float4 p = pred[idx];
    float4 g = gt[idx];
    opred[idx] = pack_fp8x4(p);
    ogt[idx]   = pack_fp8x4(g);
    float s = p.x * g.x + p.y * g.y + p.z * g.z + p.w * g.w;

    // q slice: 512 float4 per block, 2 per thread
    const int qi = row * 512 + t;
    float4 a0 = qh[qi], b0 = qr[qi];
    float4 a1 = qh[qi + 256], b1 = qr[qi + 256];
    float ls = a0.x * b0.x + a0.y * b0.y + a0.z * b0.z + a0.w * b0.w
             + a1.x * b1.x + a1.y * b1.y + a1.z * b1.z + a1.w * b1.w;

    #pragma unroll
    for (int o = 32; o > 0; o >>= 1) {
        s  += __shfl_down(s, o, 64);
        ls += __shfl_down(ls, o, 64);
    }
    if ((t & 63) == 0) { sred[t >> 6] = s; sred2[t >> 6] = ls; }
    __syncthreads();
    if (t == 0) {
        pos[row]   = sred[0] + sred[1] + sred[2] + sred[3];
        lpart[row] = sred2[0] + sred2[1] + sred2[2] + sred2[3];
    }
}

// ---------------- hinge GEMM (fp8 e4m3): sum_ij max(0, <pred_i,gt_j> - pos_i + 1) ----------------
// 128x128 block tile, BK=32, 4 waves, each wave 64x64 = 4x4 of mfma_f32_16x16x32_fp8_fp8.
// fp8 tiles are 128 rows x 32 B: half the staging bytes of bf16, and the 32 B row stride
// spreads ds_read_b64 fragment reads across banks at the b64 floor (4 lanes/bank) with
// no swizzle. Each block folds 4 prep local-loss partials before its single atomicAdd.
__global__ __launch_bounds__(256) void hinge_gemm(
    const unsigned char* __restrict__ A,    // pred_fp8 [BROWS][DDIM] row-major, 1024 B/row
    const unsigned char* __restrict__ Bm,   // gt_fp8
    const float* __restrict__ pos,          // [BROWS]
    const float* __restrict__ lpart,        // [4096]
    float* __restrict__ out) {
    __shared__ unsigned char As[128 * 32];  // 4 KB
    __shared__ unsigned char Bs[128 * 32];  // 4 KB
    __shared__ float pos_s[128];
    __shared__ float sred[4];

    const int bm = blockIdx.y;  // row block (pred rows)
    const int bn = blockIdx.x;  // col block (gt rows)
    const int tid = threadIdx.x;
    const int lane = tid & 63;
    const int wave = tid >> 6;
    const int wm = wave >> 1;   // 0..1  wave row within block tile
    const int wn = wave & 1;    // 0..1  wave col

    if (tid < 128) pos_s[tid] = pos[bm * 128 + tid];

    // staging: each tile is 4 KB = 4 chunks of 1 KB; wave w stages chunk w of A and of B.
    // lane l covers row w*32 + (l>>1), 16B half (l&1)  [matches HW dest base+16*lane]
    const int srow = wave * 32 + (lane >> 1);
    const int scol = (lane & 1) * 16;

    const unsigned char* Abase = A + (size_t)(bm * 128) * DDIM;
    const unsigned char* Bbase = Bm + (size_t)(bn * 128) * DDIM;

    f32x4 zero = {0.0f, 0.0f, 0.0f, 0.0f};
    f32x4 acc[4][4];
    #pragma unroll
    for (int i = 0; i < 4; i++)
        #pragma unroll
        for (int j = 0; j < 4; j++) acc[i][j] = zero;

    const int rsel = lane & 15;          // m (or n) index
    const int koff = (lane >> 4) * 8;    // k = quad*8 + byte

    for (int k0 = 0; k0 < DDIM; k0 += 32) {
        __builtin_amdgcn_global_load_lds(
            (gu32*)(Abase + (size_t)srow * DDIM + k0 + scol),
            (su32*)(As + wave * 1024), 16, 0, 0);
        __builtin_amdgcn_global_load_lds(
            (gu32*)(Bbase + (size_t)srow * DDIM + k0 + scol),
            (su32*)(Bs + wave * 1024), 16, 0, 0);
        __syncthreads();

        long af[4], bg[4];
        #pragma unroll
        for (int mt = 0; mt < 4; mt++)
            af[mt] = *(const long*)&As[(wm * 64 + mt * 16 + rsel) * 32 + koff];
        #pragma unroll
        for (int nt = 0; nt < 4; nt++)
            bg[nt] = *(const long*)&Bs[(wn * 64 + nt * 16 + rsel) * 32 + koff];
        #pragma unroll
        for (int mt = 0; mt < 4; mt++)
            #pragma unroll
            for (int nt = 0; nt < 4; nt++)
                acc[mt][nt] = __builtin_amdgcn_mfma_f32_16x16x32_fp8_fp8(
                    af[mt], bg[nt], acc[mt][nt], 0, 0, 0);
        __syncthreads();
    }

    // epilogue: hinge + block reduction + local-loss partial fold
    // C/D layout: col = lane&15, row = (lane>>4)*4 + reg   [dtype-independent, m89/m121]
    float s = 0.0f;
    const int rowq = (lane >> 4) * 4;
    #pragma unroll
    for (int mt = 0; mt < 4; mt++) {
        #pragma unroll
        for (int nt = 0; nt < 4; nt++) {
            #pragma unroll
            for (int r = 0; r < 4; r++) {
                int lr = wm * 64 + mt * 16 + rowq + r;  // local row in [0,128)
                float v = acc[mt][nt][r] - pos_s[lr] + 1.0f;
                s += fmaxf(v, 0.0f);
            }
        }
    }
    #pragma unroll
    for (int o = 32; o > 0; o >>= 1) s += __shfl_down(s, o, 64);
    if (lane == 0) sred[wave] = s;
    __syncthreads();
    if (tid == 0) {
        const int bid = (bm * 32 + bn) * 4;
        float lp = lpart[bid] + lpart[bid + 1] + lpart[bid + 2] + lpart[bid + 3];
        atomicAdd(out, sred[0] + sred[1] + sred[2] + sred[3]
                       - lp * (1.0f / (float)LROWS));
    }
}

extern "C" void kernel_launch(void* const* d_in, const int* in_sizes, int n_in,
                              void* d_out, int out_size, void* d_ws, size_t ws_size,
                              hipStream_t stream) {
    const float* q_hat  = (const float*)d_in[0];
    const float* q_real = (const float*)d_in[1];
    const float* gt     = (const float*)d_in[2];  // encoded_gt
    const float* pred   = (const float*)d_in[3];  // encoded_pred
    float* out = (float*)d_out;

    // workspace layout: pred_fp8 (4MB) | gt_fp8 (4MB) | pos (16KB) | lpart (16KB)
    char* ws = (char*)d_ws;
    unsigned char* pred_8 = (unsigned char*)ws;
    unsigned char* gt_8   = (unsigned char*)(ws + (size_t)BROWS * DDIM);
    float* pos   = (float*)(ws + (size_t)2 * BROWS * DDIM);
    float* lpart = (float*)(ws + (size_t)2 * BROWS * DDIM + BROWS * 4);

    hipLaunchKernelGGL(prep_kernel, dim3(BROWS), dim3(256), 0, stream,
                       (const float4*)pred, (const float4*)gt,
                       (unsigned int*)pred_8, (unsigned int*)gt_8,
                       (const float4*)q_hat, (const float4*)q_real,
                       pos, lpart, out);

    hipLaunchKernelGGL(hinge_gemm, dim3(32, 32), dim3(256), 0, stream,
                       pred_8, gt_8, pos, lpart, out);
}

// Round 5
// 146.815 us; speedup vs baseline: 1.3741x; 1.1114x over previous
//
#include <hip/hip_runtime.h>
#include <hip/hip_bf16.h>

// Problem sizes (fixed by the reference)
#define LROWS 8192
#define BROWS 4096
#define DDIM  1024

typedef __attribute__((ext_vector_type(4)))  int   i32x4;
typedef __attribute__((ext_vector_type(8)))  int   i32x8;
typedef __attribute__((ext_vector_type(16))) float f32x16;

// address-space-qualified pointer typedefs for global_load_lds
typedef const unsigned int __attribute__((address_space(1))) gu32;
typedef unsigned int       __attribute__((address_space(3))) su32;

// pack 4 floats -> 4 fp8 e4m3 bytes (OCP e4m3fn on gfx950)
__device__ inline unsigned int pack_fp8x4(float4 v) {
    unsigned int w = 0;
    w = __builtin_amdgcn_cvt_pk_fp8_f32(v.x, v.y, w, false);  // bytes 0,1
    w = __builtin_amdgcn_cvt_pk_fp8_f32(v.z, v.w, w, true);   // bytes 2,3
    return w;
}

// ---------------- prep: fp32->fp8 cast + pos diag dots + local-loss partials ----------------
// one block per pred/gt row (4096 blocks). Each block ALSO streams its 1/4096 slice of
// q_hat/q_real (512 float4 each) — pure HBM streaming at full rate here (R2/R3 lesson:
// q-loads inside the GEMM's barrier-drained K-loop can't hide). Partials go to ws;
// hinge folds them. Block 0 zero-inits out (hinge runs after in stream order).
__global__ __launch_bounds__(256) void prep_kernel(
    const float4* __restrict__ pred,
    const float4* __restrict__ gt,
    unsigned int* __restrict__ opred,   // fp8, 256 uints per row
    unsigned int* __restrict__ ogt,
    const float4* __restrict__ qh,
    const float4* __restrict__ qr,
    float* __restrict__ pos,
    float* __restrict__ lpart,          // [4096] per-block local-loss partials
    float* __restrict__ out) {
    __shared__ float sred[4], sred2[4];
    const int row = blockIdx.x;
    const int t = threadIdx.x;
    if (row == 0 && t == 0) out[0] = 0.0f;

    const int idx = row * 256 + t;
    float4 p = pred[idx];
    float4 g = gt[idx];
    opred[idx] = pack_fp8x4(p);
    ogt[idx]   = pack_fp8x4(g);
    float s = p.x * g.x + p.y * g.y + p.z * g.z + p.w * g.w;

    // q slice: 512 float4 per block, 2 per thread
    const int qi = row * 512 + t;
    float4 a0 = qh[qi], b0 = qr[qi];
    float4 a1 = qh[qi + 256], b1 = qr[qi + 256];
    float ls = a0.x * b0.x + a0.y * b0.y + a0.z * b0.z + a0.w * b0.w
             + a1.x * b1.x + a1.y * b1.y + a1.z * b1.z + a1.w * b1.w;

    #pragma unroll
    for (int o = 32; o > 0; o >>= 1) {
        s  += __shfl_down(s, o, 64);
        ls += __shfl_down(ls, o, 64);
    }
    if ((t & 63) == 0) { sred[t >> 6] = s; sred2[t >> 6] = ls; }
    __syncthreads();
    if (t == 0) {
        pos[row]   = sred[0] + sred[1] + sred[2] + sred[3];
        lpart[row] = sred2[0] + sred2[1] + sred2[2] + sred2[3];
    }
}

// ---------------- hinge GEMM (MX fp8, scales=1.0): sum_ij max(0,<p_i,g_j>-pos_i+1) ----------------
// 128x128 block tile, BK=128 staged (32 KB LDS), 4 waves, each wave 64x64 = 2x2 of
// mfma_scale_f32_32x32x64_f8f6f4 (fp8/fp8, E8M0 scale byte 0x7F = 1.0) -> 2x the
// non-scaled fp8 MFMA rate (m148: 1628 vs 995 TF).
// LDS rows are 128 B; 16B units XOR-swizzled by (row&7) so staging stays lane-uniform
// ((lane&7)^(lane>>3)) and fragment ds_read_b128s sit at the bank-capacity floor.
__global__ __launch_bounds__(256) void hinge_gemm(
    const unsigned char* __restrict__ A,    // pred_fp8 [BROWS][DDIM] row-major, 1024 B/row
    const unsigned char* __restrict__ Bm,   // gt_fp8
    const float* __restrict__ pos,          // [BROWS]
    const float* __restrict__ lpart,        // [4096]
    float* __restrict__ out) {
    __shared__ unsigned char As[128 * 128];  // 16 KB
    __shared__ unsigned char Bs[128 * 128];  // 16 KB
    __shared__ float pos_s[128];
    __shared__ float sred[4];

    const int bm = blockIdx.y;  // row block (pred rows)
    const int bn = blockIdx.x;  // col block (gt rows)
    const int tid = threadIdx.x;
    const int lane = tid & 63;
    const int wave = tid >> 6;
    const int wm = wave >> 1;   // 0..1  wave row within block tile
    const int wn = wave & 1;    // 0..1  wave col

    if (tid < 128) pos_s[tid] = pos[bm * 128 + tid];

    // staging: 32 chunks of 1 KB per matrix... actually 16 chunks (128 rows x 128 B = 16 KB).
    // wave w stages chunks w*4..w*4+3 of A and of B. Each chunk = 8 rows.
    // lane l -> row_in_chunk l>>3, phys 16B unit l&7; it fetches LOGICAL unit
    // (l&7)^(l>>3) so the tile lands swizzled: phys_unit = log_unit ^ (row&7).
    const int grow = lane >> 3;                 // 0..7
    const int usw  = (lane & 7) ^ grow;         // logical unit this lane fetches

    const unsigned char* Abase = A + (size_t)(bm * 128) * DDIM;
    const unsigned char* Bbase = Bm + (size_t)(bn * 128) * DDIM;

    f32x16 acc[2][2];
    #pragma unroll
    for (int i = 0; i < 2; i++)
        #pragma unroll
        for (int j = 0; j < 2; j++)
            #pragma unroll
            for (int r = 0; r < 16; r++) acc[i][j][r] = 0.0f;

    const int sc1 = 0x7f7f7f7f;        // E8M0 1.0 in every byte
    const int mrow = lane & 31;        // m (or n) within 32x32 tile
    const int kh = lane >> 5;          // 0..1: which 32-byte k-half of the mfma's K=64

    for (int k0 = 0; k0 < DDIM; k0 += 128) {
        #pragma unroll
        for (int i = 0; i < 4; i++) {
            int c = wave * 4 + i;           // chunk 0..15
            int row = c * 8 + grow;         // tile row 0..127
            __builtin_amdgcn_global_load_lds(
                (gu32*)(Abase + (size_t)row * DDIM + k0 + usw * 16),
                (su32*)(As + c * 1024), 16, 0, 0);
            __builtin_amdgcn_global_load_lds(
                (gu32*)(Bbase + (size_t)row * DDIM + k0 + usw * 16),
                (su32*)(Bs + c * 1024), 16, 0, 0);
        }
        __syncthreads();

        #pragma unroll
        for (int h = 0; h < 2; h++) {      // two K=64 mfma steps per staged BK=128
            const int u0 = h * 4 + kh * 2; // logical 16B unit of this lane's k-block
            i32x8 af[2], bg[2];
            #pragma unroll
            for (int mt = 0; mt < 2; mt++) {
                int r = wm * 64 + mt * 32 + mrow;
                i32x4 x0 = *(const i32x4*)&As[r * 128 + ((u0    ) ^ (r & 7)) * 16];
                i32x4 x1 = *(const i32x4*)&As[r * 128 + ((u0 + 1) ^ (r & 7)) * 16];
                af[mt] = __builtin_shufflevector(x0, x1, 0, 1, 2, 3, 4, 5, 6, 7);
            }
            #pragma unroll
            for (int nt = 0; nt < 2; nt++) {
                int r = wn * 64 + nt * 32 + mrow;
                i32x4 x0 = *(const i32x4*)&Bs[r * 128 + ((u0    ) ^ (r & 7)) * 16];
                i32x4 x1 = *(const i32x4*)&Bs[r * 128 + ((u0 + 1) ^ (r & 7)) * 16];
                bg[nt] = __builtin_shufflevector(x0, x1, 0, 1, 2, 3, 4, 5, 6, 7);
            }
            #pragma unroll
            for (int mt = 0; mt < 2; mt++)
                #pragma unroll
                for (int nt = 0; nt < 2; nt++)
                    acc[mt][nt] = __builtin_amdgcn_mfma_scale_f32_32x32x64_f8f6f4(
                        af[mt], bg[nt], acc[mt][nt],
                        0, 0,          // cbsz = A fmt fp8(e4m3), blgp = B fmt fp8
                        0, sc1,        // scale_a opsel, scale_a (1.0)
                        0, sc1);       // scale_b opsel, scale_b (1.0)
        }
        __syncthreads();
    }

    // epilogue: hinge + block reduction + local-loss partial fold
    // 32x32 C/D layout: col = lane&31, row = (reg&3) + 8*(reg>>2) + 4*(lane>>5)
    // [verified m74/m101; dtype-independent m121/m124]
    float s = 0.0f;
    const int rq = 4 * (lane >> 5);
    #pragma unroll
    for (int mt = 0; mt < 2; mt++) {
        #pragma unroll
        for (int nt = 0; nt < 2; nt++) {
            #pragma unroll
            for (int i = 0; i < 16; i++) {
                int lr = wm * 64 + mt * 32 + (i & 3) + 8 * (i >> 2) + rq;
                float v = acc[mt][nt][i] - pos_s[lr] + 1.0f;
                s += fmaxf(v, 0.0f);
            }
        }
    }
    #pragma unroll
    for (int o = 32; o > 0; o >>= 1) s += __shfl_down(s, o, 64);
    if (lane == 0) sred[wave] = s;
    __syncthreads();
    if (tid == 0) {
        const int bid = (bm * 32 + bn) * 4;
        float lp = lpart[bid] + lpart[bid + 1] + lpart[bid + 2] + lpart[bid + 3];
        atomicAdd(out, sred[0] + sred[1] + sred[2] + sred[3]
                       - lp * (1.0f / (float)LROWS));
    }
}

extern "C" void kernel_launch(void* const* d_in, const int* in_sizes, int n_in,
                              void* d_out, int out_size, void* d_ws, size_t ws_size,
                              hipStream_t stream) {
    const float* q_hat  = (const float*)d_in[0];
    const float* q_real = (const float*)d_in[1];
    const float* gt     = (const float*)d_in[2];  // encoded_gt
    const float* pred   = (const float*)d_in[3];  // encoded_pred
    float* out = (float*)d_out;

    // workspace layout: pred_fp8 (4MB) | gt_fp8 (4MB) | pos (16KB) | lpart (16KB)
    char* ws = (char*)d_ws;
    unsigned char* pred_8 = (unsigned char*)ws;
    unsigned char* gt_8   = (unsigned char*)(ws + (size_t)BROWS * DDIM);
    float* pos   = (float*)(ws + (size_t)2 * BROWS * DDIM);
    float* lpart = (float*)(ws + (size_t)2 * BROWS * DDIM + BROWS * 4);

    hipLaunchKernelGGL(prep_kernel, dim3(BROWS), dim3(256), 0, stream,
                       (const float4*)pred, (const float4*)gt,
                       (unsigned int*)pred_8, (unsigned int*)gt_8,
                       (const float4*)q_hat, (const float4*)q_real,
                       pos, lpart, out);

    hipLaunchKernelGGL(hinge_gemm, dim3(32, 32), dim3(256), 0, stream,
                       pred_8, gt_8, pos, lpart, out);
}